// Round 2
// baseline (127.444 us; speedup 1.0000x reference)
//
#include <hip/hip_runtime.h>

#define S 512
#define H 128
#define NROW 4096   // B*S
#define TI 8

// ---------------- kernel 1: projection (+ kp transpose, + qw/kw dots) ----------------
// qp[row][h]  = sum_d query[row][d]*W1[h][d] + b1[h]
// kpT[h][row] = sum_d key[row][d]  *W1[h][128+d]
// qw[row] = 0.5*sum_h qp[row][h]*W2[h];  kw[row] = 0.5*sum_h kp[row][h]*W2[h]
__global__ __launch_bounds__(256) void proj_kernel(
    const float* __restrict__ query, const float* __restrict__ key,
    const float* __restrict__ W1, const float* __restrict__ b1,
    const float* __restrict__ W2,
    float* __restrict__ qp, float* __restrict__ kpT,
    float* __restrict__ qw, float* __restrict__ kw)
{
  __shared__ float w1t[128][130];   // w1t[d][h] = W1[h][off+d]  (65KB)
  __shared__ float kt[16][132];     // transpose bounce: kt[col][h] (8.4KB)
  const int bid = blockIdx.x;       // 0..511
  const bool isq = bid < 256;
  const float* __restrict__ src = isq ? query : key;
  const int rbase = (isq ? bid : bid - 256) * 16;
  const int off = isq ? 0 : 128;
  const int tid = threadIdx.x;

  for (int idx = tid; idx < 128 * 32; idx += 256) {
    const int d4 = idx & 31, h = idx >> 5;
    const float4 v = *(const float4*)(W1 + h * 256 + off + d4 * 4);
    w1t[d4 * 4 + 0][h] = v.x;
    w1t[d4 * 4 + 1][h] = v.y;
    w1t[d4 * 4 + 2][h] = v.z;
    w1t[d4 * 4 + 3][h] = v.w;
  }
  __syncthreads();

  const int w = __builtin_amdgcn_readfirstlane(tid >> 6);
  const int lane = tid & 63;
  const int r0w = rbase + w * 4;     // this wave's 4 rows

  float acc[4][2];
  float2 bv = make_float2(0.f, 0.f);
  if (isq) bv = *(const float2*)(b1 + 2 * lane);
  #pragma unroll
  for (int r = 0; r < 4; r++) { acc[r][0] = bv.x; acc[r][1] = bv.y; }

  for (int dc = 0; dc < 128; dc += 8) {
    float qs[4][8];                  // wave-uniform
    #pragma unroll
    for (int r = 0; r < 4; r++) {
      const float* sp = src + (size_t)(r0w + r) * H + dc;
      #pragma unroll
      for (int u = 0; u < 8; u++) qs[r][u] = sp[u];
    }
    #pragma unroll
    for (int dd = 0; dd < 8; dd++) {
      const float2 wv = *(const float2*)&w1t[dc + dd][2 * lane];
      #pragma unroll
      for (int r = 0; r < 4; r++) {
        acc[r][0] = __builtin_fmaf(qs[r][dd], wv.x, acc[r][0]);
        acc[r][1] = __builtin_fmaf(qs[r][dd], wv.y, acc[r][1]);
      }
    }
  }

  // qw / kw: wave butterfly over h (lane owns h = 2*lane, 2*lane+1)
  const float2 w2p = *(const float2*)(W2 + 2 * lane);
  #pragma unroll
  for (int r = 0; r < 4; r++) {
    float t = acc[r][0] * w2p.x + acc[r][1] * w2p.y;
    #pragma unroll
    for (int m = 1; m <= 32; m <<= 1) t += __shfl_xor(t, m, 64);
    if (lane == 0) {
      float* dw = isq ? qw : kw;
      dw[r0w + r] = 0.5f * t;
    }
  }

  if (isq) {
    #pragma unroll
    for (int r = 0; r < 4; r++)
      *(float2*)(qp + (size_t)(r0w + r) * H + 2 * lane) =
          make_float2(acc[r][0], acc[r][1]);
  } else {
    #pragma unroll
    for (int r = 0; r < 4; r++)
      *(float2*)&kt[w * 4 + r][2 * lane] =
          make_float2(acc[r][0], acc[r][1]);   // 2-way bank alias: free
    __syncthreads();
    // write kpT[h][rbase + 0..15] coalesced-ish (64B per thread-pair)
    const int h = tid >> 1, seg = tid & 1;
    float tmp[8];
    #pragma unroll
    for (int c = 0; c < 8; c++) tmp[c] = kt[seg * 8 + c][h];
    float* dst = kpT + (size_t)h * NROW + rbase + seg * 8;
    *(float4*)dst = make_float4(tmp[0], tmp[1], tmp[2], tmp[3]);
    *(float4*)(dst + 4) = make_float4(tmp[4], tmp[5], tmp[6], tmp[7]);
  }
}

// ---------------- kernel 2: scores + exp + AV (partials) ----------------
// grid: x = i-tile (512), y = j-half (2). 256 threads = 4 waves; lane = j.
__global__ __launch_bounds__(256) void attn_kernel(
    const float* __restrict__ qp, const float* __restrict__ kpT,
    const float* __restrict__ qw, const float* __restrict__ kw,
    const float* __restrict__ value, const int* __restrict__ q_mask,
    const int* __restrict__ k_mask, const float* __restrict__ W2,
    const float* __restrict__ b2,
    float* __restrict__ nump, float* __restrict__ denp)
{
  __shared__ float qs[TI][128];     // q tile (broadcast reads)
  __shared__ float w2s[128];        // 0.5*W2
  __shared__ float qws[TI];
  __shared__ float aT[4][64][12];   // per-wave a bounce buffer
  __shared__ float numk[TI][132];
  __shared__ float denk[TI];

  const int it = blockIdx.x;          // 0..511
  const int jh = blockIdx.y;          // 0..1
  const int r0 = it * TI;
  const int b  = r0 >> 9;
  const int tid = threadIdx.x;
  const int w = __builtin_amdgcn_readfirstlane(tid >> 6);
  const int lane = tid & 63;
  const int jl = (jh << 8) + (w << 6) + lane;  // within-b key index
  const int jg = (b << 9) + jl;                // global key row
  const int km = k_mask[jg];
  const float kwj = kw[jg];
  const float b2v = b2[0];

  // stage q tile, scaled W2, qw
  {
    const int i = tid >> 5, c = tid & 31;
    *(float4*)&qs[i][c * 4] = *(const float4*)(qp + (size_t)(r0 + i) * H + c * 4);
    if (tid < 32) {
      float4 t = *(const float4*)(W2 + tid * 4);
      t.x *= 0.5f; t.y *= 0.5f; t.z *= 0.5f; t.w *= 0.5f;
      *(float4*)&w2s[tid * 4] = t;
    }
    if (tid < TI) qws[tid] = qw[r0 + tid];
  }
  __syncthreads();

  // ---- phase 1: s[i] = sum_h |q+k| * (W2/2)  (coalesced kpT column loads) ----
  float s[TI];
  #pragma unroll
  for (int i = 0; i < TI; i++) s[i] = 0.f;
  const float* __restrict__ kcol = kpT + jg;

  for (int hc = 0; hc < H; hc += 16) {
    float kr[16];
    #pragma unroll
    for (int u = 0; u < 16; u++) kr[u] = kcol[(hc + u) * NROW];
    float w2c[16];
    #pragma unroll
    for (int u = 0; u < 4; u++) {
      const float4 t = *(const float4*)&w2s[hc + u * 4];
      w2c[u*4+0] = t.x; w2c[u*4+1] = t.y; w2c[u*4+2] = t.z; w2c[u*4+3] = t.w;
    }
    #pragma unroll
    for (int i = 0; i < TI; i++) {
      float qv[16];
      #pragma unroll
      for (int u = 0; u < 4; u++) {
        const float4 t = *(const float4*)&qs[i][hc + u * 4];
        qv[u*4+0] = t.x; qv[u*4+1] = t.y; qv[u*4+2] = t.z; qv[u*4+3] = t.w;
      }
      #pragma unroll
      for (int u = 0; u < 16; u++) {
        const float t = qv[u] + kr[u];
        s[i] = __builtin_fmaf(fabsf(t), w2c[u], s[i]);
      }
    }
  }

  // ---- mask + exp + den reduce ----
  float a[TI], den[TI];
  #pragma unroll
  for (int i = 0; i < TI; i++) {
    const int qm = q_mask[r0 + i];
    const float sf = s[i] + qws[i] + kwj;
    a[i] = (km > 0 && qm > 0) ? __expf(sf + b2v) : 0.f;
  }
  #pragma unroll
  for (int i = 0; i < TI; i++) {
    float d = a[i];
    #pragma unroll
    for (int m = 32; m >= 1; m >>= 1) d += __shfl_xor(d, m, 64);
    den[i] = d;
  }
  #pragma unroll
  for (int i = 0; i < TI; i++) aT[w][lane][i] = a[i];
  __syncthreads();

  // ---- phase 2: num[i][h] += a[i][j]*v[j][h] over this wave's 64 j ----
  const int lj = lane >> 5, lh = lane & 31;
  float nr[TI][4];
  #pragma unroll
  for (int i = 0; i < TI; i++) { nr[i][0]=0.f; nr[i][1]=0.f; nr[i][2]=0.f; nr[i][3]=0.f; }
  const float* __restrict__ vbase =
      value + ((size_t)b * S + (jh << 8) + (w << 6)) * H;

  for (int js = 0; js < 32; js++) {
    const int j = js * 2 + lj;
    const float4 vv = *(const float4*)(vbase + (size_t)j * H + lh * 4);
    float av[TI];
    { const float4 t0 = *(const float4*)&aT[w][j][0];
      const float4 t1 = *(const float4*)&aT[w][j][4];
      av[0]=t0.x; av[1]=t0.y; av[2]=t0.z; av[3]=t0.w;
      av[4]=t1.x; av[5]=t1.y; av[6]=t1.z; av[7]=t1.w; }
    #pragma unroll
    for (int i = 0; i < TI; i++) {
      nr[i][0] = __builtin_fmaf(av[i], vv.x, nr[i][0]);
      nr[i][1] = __builtin_fmaf(av[i], vv.y, nr[i][1]);
      nr[i][2] = __builtin_fmaf(av[i], vv.z, nr[i][2]);
      nr[i][3] = __builtin_fmaf(av[i], vv.w, nr[i][3]);
    }
  }
  #pragma unroll
  for (int i = 0; i < TI; i++) {
    #pragma unroll
    for (int k = 0; k < 4; k++) nr[i][k] += __shfl_xor(nr[i][k], 32, 64);
  }

  // ---- cross-wave accumulate in LDS (deterministic rounds) ----
  for (int r = 0; r < 4; r++) {
    if (w == r) {
      if (lj == 0) {
        #pragma unroll
        for (int i = 0; i < TI; i++) {
          float4* p = (float4*)&numk[i][lh * 4];
          if (r == 0) {
            *p = make_float4(nr[i][0], nr[i][1], nr[i][2], nr[i][3]);
          } else {
            float4 t = *p;
            t.x += nr[i][0]; t.y += nr[i][1]; t.z += nr[i][2]; t.w += nr[i][3];
            *p = t;
          }
        }
      }
      if (lane == 0) {
        #pragma unroll
        for (int i = 0; i < TI; i++)
          denk[i] = (r == 0) ? den[i] : denk[i] + den[i];
      }
    }
    __syncthreads();
  }

  // ---- store partials ----
  {
    const int i = tid >> 5, seg = tid & 31;
    const float4 v = *(const float4*)&numk[i][seg * 4];
    float* dst = nump + ((size_t)jh * NROW + (size_t)(r0 + i)) * H + seg * 4;
    *(float4*)dst = v;
    if (tid < TI) denp[jh * NROW + r0 + tid] = denk[tid];
  }
}

// ---------------- kernel 3: finalize ----------------
__global__ __launch_bounds__(256) void finalize_kernel(
    const float* __restrict__ nump, const float* __restrict__ denp,
    float* __restrict__ out)
{
  const int idx = blockIdx.x * 256 + threadIdx.x;  // float4 units
  const int row = idx >> 5;
  const float4 a = *(const float4*)(nump + (size_t)idx * 4);
  const float4 c = *(const float4*)(nump + (size_t)NROW * H + (size_t)idx * 4);
  const float d = denp[row] + denp[NROW + row];
  const float inv = 1.f / fmaxf(d, 2e-15f);
  float4 o;
  o.x = (a.x + c.x) * inv; o.y = (a.y + c.y) * inv;
  o.z = (a.z + c.z) * inv; o.w = (a.w + c.w) * inv;
  *(float4*)(out + (size_t)idx * 4) = o;
}

extern "C" void kernel_launch(void* const* d_in, const int* in_sizes, int n_in,
                              void* d_out, int out_size, void* d_ws, size_t ws_size,
                              hipStream_t stream)
{
  (void)in_sizes; (void)n_in; (void)out_size; (void)ws_size;
  const float* query  = (const float*)d_in[0];
  const float* key    = (const float*)d_in[1];
  const float* value  = (const float*)d_in[2];
  const int*   q_mask = (const int*)d_in[3];
  const int*   k_mask = (const int*)d_in[4];
  const float* W1     = (const float*)d_in[5];
  const float* b1     = (const float*)d_in[6];
  const float* W2     = (const float*)d_in[7];
  const float* b2     = (const float*)d_in[8];
  float* out = (float*)d_out;

  float* ws   = (float*)d_ws;
  float* qp   = ws;                                  // [4096][128]
  float* kpT  = ws + (size_t)NROW * H;               // [128][4096]
  float* qw   = ws + (size_t)2 * NROW * H;           // [4096]
  float* kw   = qw + NROW;                           // [4096]
  float* nump = kw + NROW;                           // [2][4096][128]
  float* denp = nump + (size_t)2 * NROW * H;         // [2][4096]

  proj_kernel<<<512, 256, 0, stream>>>(query, key, W1, b1, W2, qp, kpT, qw, kw);
  attn_kernel<<<dim3(512, 2), 256, 0, stream>>>(qp, kpT, qw, kw, value, q_mask,
                                                k_mask, W2, b2, nump, denp);
  finalize_kernel<<<512, 256, 0, stream>>>(nump, denp, out);
}